// Round 7
// baseline (486.590 us; speedup 1.0000x reference)
//
#include <hip/hip_runtime.h>

#define DM 256
#define DI 512
#define NL 10

// ws offsets (floats)
#define WS_POOLED 0
#define WS_GATES  40960
#define WS_SX     122880
#define WS_SH     204800
#define WS_XC     286720
#define WS_SZ     450560

__device__ __forceinline__ float dot4(float4 a, float4 b) {
    return a.x*b.x + a.y*b.y + a.z*b.z + a.w*b.w;
}
__device__ __forceinline__ float silu(float x) {
    return x / (1.f + __expf(-x));
}

// ---------------- Kernel 1: pool (blocks 0..10239) + audio->sx copy (blocks 10240..10255)
__global__ void pool_kernel(const float* __restrict__ x1, const float* __restrict__ x2,
                            const float* __restrict__ x3, const float* __restrict__ x4,
                            const float* __restrict__ audio, float* __restrict__ ws)
{
    if (blockIdx.x >= 10240) {
        const int idx = blockIdx.x - 10240, e = idx >> 2, b = idx & 3;  // e in 0..3
        float* sx = ws + WS_SX + (e*4+b)*2560;
        for (int i = threadIdx.x; i < 2560; i += 256) sx[i] = audio[b*2560 + i];
        return;
    }
    float* pooled = ws + WS_POOLED;
    int wid  = (blockIdx.x * blockDim.x + threadIdx.x) >> 6;
    int lane = threadIdx.x & 63;
    int img = wid / 10240;
    int r   = wid % 10240;
    const float* src; int hw;
    if      (img == 0) { src = x1; hw = 3136; }
    else if (img == 1) { src = x2; hw = 784; }
    else if (img == 2) { src = x3; hw = 196; }
    else               { src = x4; hw = 49; }
    const float* row = src + (size_t)r * hw;
    float s = 0.f;
    if (hw == 49) {
        if (lane < 49) s = row[lane];
    } else {
        int n4 = hw >> 2;
        for (int j = lane; j < n4; j += 64) {
            float4 v = *(const float4*)(row + j*4);
            s += v.x + v.y + v.z + v.w;
        }
    }
    #pragma unroll
    for (int off = 32; off; off >>= 1) s += __shfl_down(s, off);
    if (lane == 0) pooled[img*10240 + r] = s / (float)hw;
}

// ---------------- Kernel 2: vis GEMM -> sx for e=4..7. grid = 256 (img,b,tile16)
__global__ __launch_bounds__(256)
void build_kernel(const float* __restrict__ vis_w, const float* __restrict__ vis_b,
                  float* __restrict__ ws)
{
    __shared__ float act[NL*DM];
    const int tid = threadIdx.x, bi = blockIdx.x;
    const int img = bi >> 6, b = (bi >> 4) & 3, tile = bi & 15;
    const float* pooled = ws + WS_POOLED + img*10240 + b*2560;
    for (int i = tid; i < 640; i += 256)
        ((float4*)act)[i] = ((const float4*)pooled)[i];
    __syncthreads();
    const int wave = tid >> 6, lane = tid & 63;
    const int c4 = lane >> 4, k16 = lane & 15;
    const int col = tile*16 + wave*4 + c4;
    const float* wp = vis_w + img*65536 + col*256 + k16*4;
    float acc[NL];
    #pragma unroll
    for (int l = 0; l < NL; l++) acc[l] = 0.f;
    #pragma unroll
    for (int ko = 0; ko < 4; ko++) {
        float4 wv = *(const float4*)(wp + ko*64);
        #pragma unroll
        for (int l = 0; l < NL; l++)
            acc[l] += dot4(wv, *(const float4*)(&act[l*256 + ko*64 + k16*4]));
    }
    #pragma unroll
    for (int l = 0; l < NL; l++) {
        acc[l] += __shfl_xor(acc[l], 1);
        acc[l] += __shfl_xor(acc[l], 2);
        acc[l] += __shfl_xor(acc[l], 4);
        acc[l] += __shfl_xor(acc[l], 8);
    }
    if (k16 == 0) {
        float bias = vis_b[img*256 + col];
        float* sx = ws + WS_SX + ((img+4)*4+b)*2560;
        #pragma unroll
        for (int l = 0; l < NL; l++) sx[l*256 + col] = bias + acc[l];
    }
}

// ---------------- Kernel 3 (stage A): [layer0: LN] + xz GEMM + conv/silu | z-silu.
// grid = 8e*4b*64tile = 2048 blocks, 256 thr.
__global__ __launch_bounds__(256)
void lnxz_kernel(const float* __restrict__ ln_g, const float* __restrict__ ln_b,
                 const float* __restrict__ in_w, const float* __restrict__ conv_w,
                 const float* __restrict__ conv_b, float* __restrict__ ws, int layer)
{
    __shared__ float act[NL*DM];     // LN'd activations for this (e,b)
    const int tid = threadIdx.x, bi = blockIdx.x;
    const int e = bi >> 8, b = (bi >> 6) & 3, tile = bi & 63;
    const int el = e*3 + layer;
    const int wave = tid >> 6, lane = tid & 63;
    float* shg = ws + WS_SH + (e*4+b)*2560;

    if (layer == 0) {
        const float* sx = ws + WS_SX + (e*4+b)*2560;
        for (int l = wave; l < NL; l += 4) {
            float4 v = *(const float4*)(sx + l*256 + lane*4);
            float s = v.x+v.y+v.z+v.w, ss = dot4(v, v);
            #pragma unroll
            for (int off = 32; off; off >>= 1) { s += __shfl_xor(s, off); ss += __shfl_xor(ss, off); }
            float m = s * (1.f/256.f);
            float rs = rsqrtf(ss*(1.f/256.f) - m*m + 1e-5f);
            float4 gv = *(const float4*)(ln_g + el*256 + lane*4);
            float4 bv = *(const float4*)(ln_b + el*256 + lane*4);
            float4 hv;
            hv.x = (v.x-m)*rs*gv.x + bv.x;
            hv.y = (v.y-m)*rs*gv.y + bv.y;
            hv.z = (v.z-m)*rs*gv.z + bv.z;
            hv.w = (v.w-m)*rs*gv.w + bv.w;
            *(float4*)(&act[l*256 + lane*4]) = hv;
            if (tile == 0) *(float4*)(shg + l*256 + lane*4) = hv;
        }
    } else {
        for (int i = tid; i < 640; i += 256)
            ((float4*)act)[i] = ((const float4*)shg)[i];
    }
    __syncthreads();

    const int c4 = lane >> 4, k16 = lane & 15;
    const int col = tile*16 + wave*4 + c4;               // 0..1023
    const float* wp = in_w + (size_t)el*262144 + (size_t)col*256 + k16*4;
    float acc[NL];
    #pragma unroll
    for (int l = 0; l < NL; l++) acc[l] = 0.f;
    #pragma unroll
    for (int ko = 0; ko < 4; ko++) {
        float4 wv = *(const float4*)(wp + ko*64);
        #pragma unroll
        for (int l = 0; l < NL; l++)
            acc[l] += dot4(wv, *(const float4*)(&act[l*256 + ko*64 + k16*4]));
    }
    #pragma unroll
    for (int l = 0; l < NL; l++) {
        acc[l] += __shfl_xor(acc[l], 1);
        acc[l] += __shfl_xor(acc[l], 2);
        acc[l] += __shfl_xor(acc[l], 4);
        acc[l] += __shfl_xor(acc[l], 8);
    }
    if (k16 == 0) {
        if (col < 512) {
            float4 cw = *(const float4*)(conv_w + el*2048 + col*4);
            float cb = conv_b[el*512 + col];
            float* xc = ws + WS_XC + (e*4+b)*5120;
            float x0 = 0.f, x1 = 0.f, x2 = 0.f;
            #pragma unroll
            for (int l = 0; l < NL; l++) {
                float x3 = acc[l];
                float a = cb + x3*cw.w + x2*cw.z + x1*cw.y + x0*cw.x;
                xc[l*512 + col] = silu(a);
                x0 = x1; x1 = x2; x2 = x3;
            }
        } else {
            float* sz = ws + WS_SZ + (e*4+b)*5120;
            const int d = col - 512;
            #pragma unroll
            for (int l = 0; l < NL; l++) sz[l*512 + d] = silu(acc[l]);
        }
    }
}

// ---------------- Kernel 4 (stage B): dbl GEMM + scan + out GEMM + residual
// + [layer<2: next-layer LN -> shg] or [layer==2: gate GEMM -> gates].
// grid = 32 (e,b), 512 thr (8 waves).
__global__ __launch_bounds__(512)
void stageB_kernel(const float* __restrict__ xp_w, const float* __restrict__ dt_w,
                   const float* __restrict__ dt_b, const float* __restrict__ A_log,
                   const float* __restrict__ Dp,   const float* __restrict__ out_w,
                   const float* __restrict__ ln_g, const float* __restrict__ ln_b,
                   const float* __restrict__ gate_w, const float* __restrict__ gate_b,
                   float* __restrict__ ws, int layer)
{
    __shared__ float xc_l[NL*DI];    // 20 KB
    __shared__ float y2_l[NL*DI];    // 20 KB
    __shared__ float dbl_l[NL*48];
    __shared__ float sxn[NL*DM];     // 10 KB
    const int tid = threadIdx.x, bi = blockIdx.x;
    const int e = bi >> 2, b = bi & 3;
    const int el = e*3 + layer;
    const int wave = tid >> 6, lane = tid & 63;
    const int c4 = lane >> 4, k16 = lane & 15;
    const float* xc = ws + WS_XC + bi*5120;
    const float* sz = ws + WS_SZ + bi*5120;
    float* shg = ws + WS_SH + bi*2560;

    for (int i = tid; i < 1280; i += 512)
        ((float4*)xc_l)[i] = ((const float4*)xc)[i];
    __syncthreads();

    // ---- dbl GEMM: 120 tasks (l, 4-row group), 15 per wave
    for (int i = 0; i < 15; i++) {
        int t = wave*15 + i;
        int l = t / 12, rg = t % 12;
        int r = rg*4 + c4;
        const float* wrow = xp_w + el*24576 + r*512 + k16*4;
        float p = 0.f;
        #pragma unroll
        for (int ko = 0; ko < 8; ko++)
            p += dot4(*(const float4*)(wrow + ko*64),
                      *(const float4*)(&xc_l[l*512 + ko*64 + k16*4]));
        p += __shfl_xor(p, 1);
        p += __shfl_xor(p, 2);
        p += __shfl_xor(p, 4);
        p += __shfl_xor(p, 8);
        if (k16 == 0) dbl_l[l*48 + r] = p;
    }
    __syncthreads();

    // ---- delta -> softplus -> scan -> y2 (LDS)
    {
        const int d = tid;
        const float* dwp = dt_w + el*8192 + d*16;
        float4 dw0 = *(const float4*)(dwp);
        float4 dw1 = *(const float4*)(dwp + 4);
        float4 dw2 = *(const float4*)(dwp + 8);
        float4 dw3 = *(const float4*)(dwp + 12);
        float dbv = dt_b[el*512 + d];
        float Dpv = Dp[el*512 + d];
        float Av[16];
        #pragma unroll
        for (int n = 0; n < 16; n++) Av[n] = -__expf(A_log[el*8192 + d*16 + n]);
        float h[16];
        #pragma unroll
        for (int n = 0; n < 16; n++) h[n] = 0.f;
        #pragma unroll
        for (int l = 0; l < NL; l++) {
            float4 t0 = *(const float4*)(&dbl_l[l*48]);
            float4 t1 = *(const float4*)(&dbl_l[l*48 + 4]);
            float4 t2 = *(const float4*)(&dbl_l[l*48 + 8]);
            float4 t3 = *(const float4*)(&dbl_l[l*48 + 12]);
            float a = dbv + dot4(t0,dw0) + dot4(t1,dw1) + dot4(t2,dw2) + dot4(t3,dw3);
            float dl = fmaxf(a, 0.f) + log1pf(__expf(-fabsf(a)));
            float xcv = xc_l[l*512 + d];
            float du = dl * xcv;
            float y = 0.f;
            #pragma unroll
            for (int n = 0; n < 16; n++) {
                float Bn = dbl_l[l*48 + 16 + n];
                float Cn = dbl_l[l*48 + 32 + n];
                h[n] = __expf(dl*Av[n])*h[n] + du*Bn;
                y += h[n]*Cn;
            }
            y2_l[l*512 + d] = (y + xcv*Dpv) * sz[l*512 + d];
        }
    }
    __syncthreads();

    // ---- out GEMM + residual -> sxn (LDS). 64 col-groups, 8 per wave.
    for (int i = 0; i < 8; i++) {
        int col = (wave*8 + i)*4 + c4;                 // 0..255
        const float* wp = out_w + (size_t)el*131072 + (size_t)col*512 + k16*4;
        float acc[NL];
        #pragma unroll
        for (int l = 0; l < NL; l++) acc[l] = 0.f;
        #pragma unroll
        for (int ko = 0; ko < 8; ko++) {
            float4 wv = *(const float4*)(wp + ko*64);
            #pragma unroll
            for (int l = 0; l < NL; l++)
                acc[l] += dot4(wv, *(const float4*)(&y2_l[l*512 + ko*64 + k16*4]));
        }
        #pragma unroll
        for (int l = 0; l < NL; l++) {
            acc[l] += __shfl_xor(acc[l], 1);
            acc[l] += __shfl_xor(acc[l], 2);
            acc[l] += __shfl_xor(acc[l], 4);
            acc[l] += __shfl_xor(acc[l], 8);
        }
        if (k16 == 0) {
            #pragma unroll
            for (int l = 0; l < NL; l++)
                sxn[l*256 + col] = shg[l*256 + col] + acc[l];
        }
    }
    __syncthreads();

    if (layer < 2) {
        // ---- next-layer LN: rows l = wave (+8). write shg.
        const int el2 = el + 1;
        #pragma unroll
        for (int p = 0; p < 2; p++) {
            int l = wave + p*8;
            if (l < NL) {
                float4 v = *(const float4*)(&sxn[l*256 + lane*4]);
                float s = v.x+v.y+v.z+v.w, ss = dot4(v, v);
                #pragma unroll
                for (int off = 32; off; off >>= 1) { s += __shfl_xor(s, off); ss += __shfl_xor(ss, off); }
                float m = s * (1.f/256.f);
                float rs = rsqrtf(ss*(1.f/256.f) - m*m + 1e-5f);
                float4 gv = *(const float4*)(ln_g + el2*256 + lane*4);
                float4 bv = *(const float4*)(ln_b + el2*256 + lane*4);
                float4 hv;
                hv.x = (v.x-m)*rs*gv.x + bv.x;
                hv.y = (v.y-m)*rs*gv.y + bv.y;
                hv.z = (v.z-m)*rs*gv.z + bv.z;
                hv.w = (v.w-m)*rs*gv.w + bv.w;
                *(float4*)(shg + l*256 + lane*4) = hv;
            }
        }
    } else {
        // ---- gate GEMM + silu -> gates. 64 col-groups, 8 per wave. K=256.
        float* gates = ws + WS_GATES;
        for (int i = 0; i < 8; i++) {
            int col = (wave*8 + i)*4 + c4;
            const float* wp = gate_w + e*65536 + col*256 + k16*4;
            float acc[NL];
            #pragma unroll
            for (int l = 0; l < NL; l++) acc[l] = 0.f;
            #pragma unroll
            for (int ko = 0; ko < 4; ko++) {
                float4 wv = *(const float4*)(wp + ko*64);
                #pragma unroll
                for (int l = 0; l < NL; l++)
                    acc[l] += dot4(wv, *(const float4*)(&sxn[l*256 + ko*64 + k16*4]));
            }
            #pragma unroll
            for (int l = 0; l < NL; l++) {
                acc[l] += __shfl_xor(acc[l], 1);
                acc[l] += __shfl_xor(acc[l], 2);
                acc[l] += __shfl_xor(acc[l], 4);
                acc[l] += __shfl_xor(acc[l], 8);
            }
            if (k16 == 0) {
                float gb = gate_b[e*256 + col];
                #pragma unroll
                for (int l = 0; l < NL; l++)
                    gates[(e*40 + b*10 + l)*256 + col] = silu(gb + acc[l]);
            }
        }
    }
}

// ---------------- Kernel 5: x_out = x*(1+gate), plus ao tail blocks
__global__ void scale_ao_kernel(const float* __restrict__ x1, const float* __restrict__ x2,
                                const float* __restrict__ x3, const float* __restrict__ x4,
                                const float* __restrict__ audio,
                                const float* __restrict__ gates, float* __restrict__ out)
{
    int wid  = (blockIdx.x * blockDim.x + threadIdx.x) >> 6;
    int lane = threadIdx.x & 63;
    if (wid >= 41120) return;
    if (wid >= 40960) {
        int i = (wid - 40960)*64 + lane;
        int bt = i >> 8, c = i & 255;
        int lb = (bt & 3)*10 + (bt >> 2);
        float vg = 0.25f * (gates[(160 + lb)*256 + c] + gates[(200 + lb)*256 + c] +
                            gates[(240 + lb)*256 + c] + gates[(280 + lb)*256 + c]);
        out[42649600 + i] = audio[i] * (1.f + vg);
        return;
    }
    int t = wid / 10240, r = wid % 10240;
    int bt = r >> 8, c = r & 255;
    int lb = (bt & 3)*10 + (bt >> 2);
    const float* src; int hw; size_t obase; int gidx;
    if      (t == 0) { src = x4; hw = 49;   obase = 0;        gidx = (120 + lb)*256 + c; }
    else if (t == 1) { src = x3; hw = 196;  obase = 501760;   gidx = ( 80 + lb)*256 + c; }
    else if (t == 2) { src = x2; hw = 784;  obase = 2508800;  gidx = ( 40 + lb)*256 + c; }
    else             { src = x1; hw = 3136; obase = 10536960; gidx = r; }
    float scale = 1.f + gates[gidx];
    const float* row = src + (size_t)r * hw;
    float* orow = out + obase + (size_t)r * hw;
    if (hw == 49) {
        if (lane < 49) orow[lane] = row[lane] * scale;
    } else {
        int n4 = hw >> 2;
        for (int j = lane; j < n4; j += 64) {
            float4 v = *(const float4*)(row + j*4);
            v.x *= scale; v.y *= scale; v.z *= scale; v.w *= scale;
            *(float4*)(orow + j*4) = v;
        }
    }
}

extern "C" void kernel_launch(void* const* d_in, const int* in_sizes, int n_in,
                              void* d_out, int out_size, void* d_ws, size_t ws_size,
                              hipStream_t stream)
{
    const float* x1     = (const float*)d_in[0];
    const float* x2     = (const float*)d_in[1];
    const float* x3     = (const float*)d_in[2];
    const float* x4     = (const float*)d_in[3];
    const float* audio  = (const float*)d_in[4];
    const float* vis_w  = (const float*)d_in[5];
    const float* vis_b  = (const float*)d_in[6];
    const float* ln_g   = (const float*)d_in[7];
    const float* ln_b   = (const float*)d_in[8];
    const float* in_w   = (const float*)d_in[9];
    const float* conv_w = (const float*)d_in[10];
    const float* conv_b = (const float*)d_in[11];
    const float* xp_w   = (const float*)d_in[12];
    const float* dt_w   = (const float*)d_in[13];
    const float* dt_b   = (const float*)d_in[14];
    const float* A_log  = (const float*)d_in[15];
    const float* Dp     = (const float*)d_in[16];
    const float* out_w  = (const float*)d_in[17];
    const float* gate_w = (const float*)d_in[18];
    const float* gate_b = (const float*)d_in[19];

    float* ws  = (float*)d_ws;
    float* out = (float*)d_out;

    pool_kernel<<<dim3(10256), dim3(256), 0, stream>>>(x1, x2, x3, x4, audio, ws);
    build_kernel<<<dim3(256), dim3(256), 0, stream>>>(vis_w, vis_b, ws);
    for (int layer = 0; layer < 3; layer++) {
        lnxz_kernel<<<dim3(2048), dim3(256), 0, stream>>>(ln_g, ln_b, in_w, conv_w,
                                                          conv_b, ws, layer);
        stageB_kernel<<<dim3(32), dim3(512), 0, stream>>>(xp_w, dt_w, dt_b, A_log, Dp,
                                                          out_w, ln_g, ln_b, gate_w,
                                                          gate_b, ws, layer);
    }
    scale_ao_kernel<<<dim3(10280), dim3(256), 0, stream>>>(x1, x2, x3, x4, audio,
                                                           ws + WS_GATES, out);
}

// Round 8
// 218.557 us; speedup vs baseline: 2.2264x; 2.2264x over previous
//
#include <hip/hip_runtime.h>

#define DM 256
#define DI 512
#define NL 10

// ws offsets (floats)
#define WS_POOLED 0
#define WS_GATES  40960
#define WS_SX     122880
#define WS_SH     204800
#define WS_XC     286720
#define WS_SZ     450560
#define WS_Y2     614400
#define WS_DBL    778240

__device__ __forceinline__ float dot4(float4 a, float4 b) {
    return a.x*b.x + a.y*b.y + a.z*b.z + a.w*b.w;
}
__device__ __forceinline__ float silu(float x) {
    return x / (1.f + __expf(-x));
}

// ---------------- Kernel 1: pool (blocks 0..10239) + audio->sx copy (10240..10255)
__global__ void pool_kernel(const float* __restrict__ x1, const float* __restrict__ x2,
                            const float* __restrict__ x3, const float* __restrict__ x4,
                            const float* __restrict__ audio, float* __restrict__ ws)
{
    if (blockIdx.x >= 10240) {
        const int idx = blockIdx.x - 10240, e = idx >> 2, b = idx & 3;  // e in 0..3
        float* sx = ws + WS_SX + (e*4+b)*2560;
        for (int i = threadIdx.x; i < 2560; i += 256) sx[i] = audio[b*2560 + i];
        return;
    }
    float* pooled = ws + WS_POOLED;
    int wid  = (blockIdx.x * blockDim.x + threadIdx.x) >> 6;
    int lane = threadIdx.x & 63;
    int img = wid / 10240;
    int r   = wid % 10240;
    const float* src; int hw;
    if      (img == 0) { src = x1; hw = 3136; }
    else if (img == 1) { src = x2; hw = 784; }
    else if (img == 2) { src = x3; hw = 196; }
    else               { src = x4; hw = 49; }
    const float* row = src + (size_t)r * hw;
    float s = 0.f;
    if (hw == 49) {
        if (lane < 49) s = row[lane];
    } else {
        int n4 = hw >> 2;
        for (int j = lane; j < n4; j += 64) {
            float4 v = *(const float4*)(row + j*4);
            s += v.x + v.y + v.z + v.w;
        }
    }
    #pragma unroll
    for (int off = 32; off; off >>= 1) s += __shfl_down(s, off);
    if (lane == 0) pooled[img*10240 + r] = s / (float)hw;
}

// ---------------- Kernel 2: vis GEMM -> sx for e=4..7. grid = 256 (img,b,tile16)
__global__ __launch_bounds__(256)
void build_kernel(const float* __restrict__ vis_w, const float* __restrict__ vis_b,
                  float* __restrict__ ws)
{
    __shared__ float act[NL*DM];
    const int tid = threadIdx.x, bi = blockIdx.x;
    const int img = bi >> 6, b = (bi >> 4) & 3, tile = bi & 15;
    const float* pooled = ws + WS_POOLED + img*10240 + b*2560;
    for (int i = tid; i < 640; i += 256)
        ((float4*)act)[i] = ((const float4*)pooled)[i];
    __syncthreads();
    const int wave = tid >> 6, lane = tid & 63;
    const int c4 = lane >> 4, k16 = lane & 15;
    const int col = tile*16 + wave*4 + c4;
    const float* wp = vis_w + img*65536 + col*256 + k16*4;
    float acc[NL];
    #pragma unroll
    for (int l = 0; l < NL; l++) acc[l] = 0.f;
    #pragma unroll
    for (int ko = 0; ko < 4; ko++) {
        float4 wv = *(const float4*)(wp + ko*64);
        #pragma unroll
        for (int l = 0; l < NL; l++)
            acc[l] += dot4(wv, *(const float4*)(&act[l*256 + ko*64 + k16*4]));
    }
    #pragma unroll
    for (int l = 0; l < NL; l++) {
        acc[l] += __shfl_xor(acc[l], 1);
        acc[l] += __shfl_xor(acc[l], 2);
        acc[l] += __shfl_xor(acc[l], 4);
        acc[l] += __shfl_xor(acc[l], 8);
    }
    if (k16 == 0) {
        float bias = vis_b[img*256 + col];
        float* sx = ws + WS_SX + ((img+4)*4+b)*2560;
        #pragma unroll
        for (int l = 0; l < NL; l++) sx[l*256 + col] = bias + acc[l];
    }
}

// ---------------- Kernel 3: LN + xz GEMM + conv/silu | z-silu.
// grid = 8e*4b*64tile = 2048 blocks, 256 thr.
__global__ __launch_bounds__(256)
void lnxz_kernel(const float* __restrict__ ln_g, const float* __restrict__ ln_b,
                 const float* __restrict__ in_w, const float* __restrict__ conv_w,
                 const float* __restrict__ conv_b, float* __restrict__ ws, int layer)
{
    __shared__ float act[NL*DM];
    const int tid = threadIdx.x, bi = blockIdx.x;
    const int e = bi >> 8, b = (bi >> 6) & 3, tile = bi & 63;
    const int el = e*3 + layer;
    const int wave = tid >> 6, lane = tid & 63;
    const float* sx = ws + WS_SX + (e*4+b)*2560;
    float* shg = ws + WS_SH + (e*4+b)*2560;

    for (int l = wave; l < NL; l += 4) {
        float4 v = *(const float4*)(sx + l*256 + lane*4);
        float s = v.x+v.y+v.z+v.w, ss = dot4(v, v);
        #pragma unroll
        for (int off = 32; off; off >>= 1) { s += __shfl_xor(s, off); ss += __shfl_xor(ss, off); }
        float m = s * (1.f/256.f);
        float rs = rsqrtf(ss*(1.f/256.f) - m*m + 1e-5f);
        float4 gv = *(const float4*)(ln_g + el*256 + lane*4);
        float4 bv = *(const float4*)(ln_b + el*256 + lane*4);
        float4 hv;
        hv.x = (v.x-m)*rs*gv.x + bv.x;
        hv.y = (v.y-m)*rs*gv.y + bv.y;
        hv.z = (v.z-m)*rs*gv.z + bv.z;
        hv.w = (v.w-m)*rs*gv.w + bv.w;
        *(float4*)(&act[l*256 + lane*4]) = hv;
        if (tile == 0) *(float4*)(shg + l*256 + lane*4) = hv;
    }
    __syncthreads();

    const int c4 = lane >> 4, k16 = lane & 15;
    const int col = tile*16 + wave*4 + c4;               // 0..1023
    const float* wp = in_w + (size_t)el*262144 + (size_t)col*256 + k16*4;
    float acc[NL];
    #pragma unroll
    for (int l = 0; l < NL; l++) acc[l] = 0.f;
    #pragma unroll
    for (int ko = 0; ko < 4; ko++) {
        float4 wv = *(const float4*)(wp + ko*64);
        #pragma unroll
        for (int l = 0; l < NL; l++)
            acc[l] += dot4(wv, *(const float4*)(&act[l*256 + ko*64 + k16*4]));
    }
    #pragma unroll
    for (int l = 0; l < NL; l++) {
        acc[l] += __shfl_xor(acc[l], 1);
        acc[l] += __shfl_xor(acc[l], 2);
        acc[l] += __shfl_xor(acc[l], 4);
        acc[l] += __shfl_xor(acc[l], 8);
    }
    if (k16 == 0) {
        if (col < 512) {
            float4 cw = *(const float4*)(conv_w + el*2048 + col*4);
            float cb = conv_b[el*512 + col];
            float* xc = ws + WS_XC + (e*4+b)*5120;
            float x0 = 0.f, x1 = 0.f, x2 = 0.f;
            #pragma unroll
            for (int l = 0; l < NL; l++) {
                float x3 = acc[l];
                float a = cb + x3*cw.w + x2*cw.z + x1*cw.y + x0*cw.x;
                xc[l*512 + col] = silu(a);
                x0 = x1; x1 = x2; x2 = x3;
            }
        } else {
            float* sz = ws + WS_SZ + (e*4+b)*5120;
            const int d = col - 512;
            #pragma unroll
            for (int l = 0; l < NL; l++) sz[l*512 + d] = silu(acc[l]);
        }
    }
}

// ---------------- Kernel 4: dbl GEMM. grid = 256 blocks = (e,b,s8), 256 thr.
// block computes rows r = s*6..s*6+5 for all 10 l.
__global__ __launch_bounds__(256)
void dbl_kernel(const float* __restrict__ xp_w, float* __restrict__ ws, int layer)
{
    __shared__ float xc_l[NL*DI];    // 20 KB
    const int tid = threadIdx.x, bi = blockIdx.x;
    const int e = bi >> 5, b = (bi >> 3) & 3, s = bi & 7;
    const int el = e*3 + layer;
    const float* xc = ws + WS_XC + (e*4+b)*5120;
    for (int i = tid; i < 1280; i += 256)
        ((float4*)xc_l)[i] = ((const float4*)xc)[i];
    __syncthreads();

    const int wave = tid >> 6, lane = tid & 63;
    const int c4 = lane >> 4, k16 = lane & 15;
    float* dbl = ws + WS_DBL + (e*4+b)*480;
    #pragma unroll
    for (int i = 0; i < 4; i++) {
        int t = wave*16 + i*4 + c4;                   // 0..63
        if (t < 60) {
            int l = t / 6, r = s*6 + t % 6;
            const float* wp = xp_w + el*24576 + r*512 + k16*4;
            float p = 0.f;
            #pragma unroll
            for (int ko = 0; ko < 8; ko++)
                p += dot4(*(const float4*)(wp + ko*64),
                          *(const float4*)(&xc_l[l*512 + ko*64 + k16*4]));
            p += __shfl_xor(p, 1);
            p += __shfl_xor(p, 2);
            p += __shfl_xor(p, 4);
            p += __shfl_xor(p, 8);
            if (k16 == 0) dbl[l*48 + r] = p;
        }
    }
}

// ---------------- Kernel 5: softplus + scan + z-gate -> y2.
// grid = 128 blocks = (e,b,ch4), 128 thr; d = ch*128 + tid.
__global__ __launch_bounds__(128)
void scan_kernel(const float* __restrict__ dt_w, const float* __restrict__ dt_b,
                 const float* __restrict__ A_log, const float* __restrict__ Dp,
                 float* __restrict__ ws, int layer)
{
    __shared__ float dbl_l[NL*48];
    const int tid = threadIdx.x, bi = blockIdx.x;
    const int e = bi >> 4, b = (bi >> 2) & 3, ch = bi & 3;
    const int el = e*3 + layer;
    const int eb = e*4 + b;
    for (int i = tid; i < 480; i += 128) dbl_l[i] = ws[WS_DBL + eb*480 + i];
    __syncthreads();

    const int d = ch*128 + tid;
    const float* dwp = dt_w + el*8192 + d*16;
    float4 dw0 = *(const float4*)(dwp);
    float4 dw1 = *(const float4*)(dwp + 4);
    float4 dw2 = *(const float4*)(dwp + 8);
    float4 dw3 = *(const float4*)(dwp + 12);
    float dbv = dt_b[el*512 + d];
    float Dpv = Dp[el*512 + d];
    float Av[16];
    #pragma unroll
    for (int n = 0; n < 16; n++) Av[n] = -__expf(A_log[el*8192 + d*16 + n]);
    const float* xc = ws + WS_XC + eb*5120;
    const float* sz = ws + WS_SZ + eb*5120;
    float* y2 = ws + WS_Y2 + eb*5120;
    float h[16];
    #pragma unroll
    for (int n = 0; n < 16; n++) h[n] = 0.f;
    #pragma unroll
    for (int l = 0; l < NL; l++) {
        float4 t0 = *(const float4*)(&dbl_l[l*48]);
        float4 t1 = *(const float4*)(&dbl_l[l*48 + 4]);
        float4 t2 = *(const float4*)(&dbl_l[l*48 + 8]);
        float4 t3 = *(const float4*)(&dbl_l[l*48 + 12]);
        float a = dbv + dot4(t0,dw0) + dot4(t1,dw1) + dot4(t2,dw2) + dot4(t3,dw3);
        float dl = fmaxf(a, 0.f) + log1pf(__expf(-fabsf(a)));
        float xcv = xc[l*512 + d];
        float du = dl * xcv;
        float y = 0.f;
        #pragma unroll
        for (int n = 0; n < 16; n++) {
            float Bn = dbl_l[l*48 + 16 + n];
            float Cn = dbl_l[l*48 + 32 + n];
            h[n] = __expf(dl*Av[n])*h[n] + du*Bn;
            y += h[n]*Cn;
        }
        y2[l*512 + d] = (y + xcv*Dpv) * sz[l*512 + d];
    }
}

// ---------------- Kernel 6: out GEMM + residual (sx = sh + y2 @ out_w.T).
// grid = 512 blocks (e,b,tile16), 256 thr. K=512.
__global__ __launch_bounds__(256)
void out_kernel(const float* __restrict__ out_w, float* __restrict__ ws, int layer)
{
    __shared__ float act[NL*DI];     // 20 KB
    const int tid = threadIdx.x, bi = blockIdx.x;
    const int e = bi >> 6, b = (bi >> 4) & 3, tile = bi & 15;
    const int el = e*3 + layer;
    const float* y2 = ws + WS_Y2 + (e*4+b)*5120;
    for (int i = tid; i < 1280; i += 256)
        ((float4*)act)[i] = ((const float4*)y2)[i];
    __syncthreads();

    const int wave = tid >> 6, lane = tid & 63;
    const int c4 = lane >> 4, k16 = lane & 15;
    const int col = tile*16 + wave*4 + c4;                // 0..255
    const float* wp = out_w + (size_t)el*131072 + (size_t)col*512 + k16*4;
    float acc[NL];
    #pragma unroll
    for (int l = 0; l < NL; l++) acc[l] = 0.f;
    #pragma unroll
    for (int ko = 0; ko < 8; ko++) {
        float4 wv = *(const float4*)(wp + ko*64);
        #pragma unroll
        for (int l = 0; l < NL; l++)
            acc[l] += dot4(wv, *(const float4*)(&act[l*512 + ko*64 + k16*4]));
    }
    #pragma unroll
    for (int l = 0; l < NL; l++) {
        acc[l] += __shfl_xor(acc[l], 1);
        acc[l] += __shfl_xor(acc[l], 2);
        acc[l] += __shfl_xor(acc[l], 4);
        acc[l] += __shfl_xor(acc[l], 8);
    }
    if (k16 == 0) {
        const float* sh = ws + WS_SH + (e*4+b)*2560;
        float* sx = ws + WS_SX + (e*4+b)*2560;
        #pragma unroll
        for (int l = 0; l < NL; l++) sx[l*256 + col] = sh[l*256 + col] + acc[l];
    }
}

// ---------------- Kernel 7: gate GEMM + silu. grid = 512 blocks (e,b,tile16), 256 thr.
__global__ __launch_bounds__(256)
void gate_kernel(const float* __restrict__ gate_w, const float* __restrict__ gate_b,
                 float* __restrict__ ws)
{
    __shared__ float act[NL*DM];
    const int tid = threadIdx.x, bi = blockIdx.x;
    const int e = bi >> 6, b = (bi >> 4) & 3, tile = bi & 15;
    const float* sx = ws + WS_SX + (e*4+b)*2560;
    for (int i = tid; i < 640; i += 256)
        ((float4*)act)[i] = ((const float4*)sx)[i];
    __syncthreads();

    const int wave = tid >> 6, lane = tid & 63;
    const int c4 = lane >> 4, k16 = lane & 15;
    const int col = tile*16 + wave*4 + c4;
    const float* wp = gate_w + e*65536 + col*256 + k16*4;
    float acc[NL];
    #pragma unroll
    for (int l = 0; l < NL; l++) acc[l] = 0.f;
    #pragma unroll
    for (int ko = 0; ko < 4; ko++) {
        float4 wv = *(const float4*)(wp + ko*64);
        #pragma unroll
        for (int l = 0; l < NL; l++)
            acc[l] += dot4(wv, *(const float4*)(&act[l*256 + ko*64 + k16*4]));
    }
    #pragma unroll
    for (int l = 0; l < NL; l++) {
        acc[l] += __shfl_xor(acc[l], 1);
        acc[l] += __shfl_xor(acc[l], 2);
        acc[l] += __shfl_xor(acc[l], 4);
        acc[l] += __shfl_xor(acc[l], 8);
    }
    if (k16 == 0) {
        float gb = gate_b[e*256 + col];
        float* gates = ws + WS_GATES;
        #pragma unroll
        for (int l = 0; l < NL; l++)
            gates[(e*40 + b*10 + l)*256 + col] = silu(gb + acc[l]);
    }
}

// ---------------- Kernel 8: x_out = x*(1+gate), plus ao tail blocks
__global__ void scale_ao_kernel(const float* __restrict__ x1, const float* __restrict__ x2,
                                const float* __restrict__ x3, const float* __restrict__ x4,
                                const float* __restrict__ audio,
                                const float* __restrict__ gates, float* __restrict__ out)
{
    int wid  = (blockIdx.x * blockDim.x + threadIdx.x) >> 6;
    int lane = threadIdx.x & 63;
    if (wid >= 41120) return;
    if (wid >= 40960) {
        int i = (wid - 40960)*64 + lane;
        int bt = i >> 8, c = i & 255;
        int lb = (bt & 3)*10 + (bt >> 2);
        float vg = 0.25f * (gates[(160 + lb)*256 + c] + gates[(200 + lb)*256 + c] +
                            gates[(240 + lb)*256 + c] + gates[(280 + lb)*256 + c]);
        out[42649600 + i] = audio[i] * (1.f + vg);
        return;
    }
    int t = wid / 10240, r = wid % 10240;
    int bt = r >> 8, c = r & 255;
    int lb = (bt & 3)*10 + (bt >> 2);
    const float* src; int hw; size_t obase; int gidx;
    if      (t == 0) { src = x4; hw = 49;   obase = 0;        gidx = (120 + lb)*256 + c; }
    else if (t == 1) { src = x3; hw = 196;  obase = 501760;   gidx = ( 80 + lb)*256 + c; }
    else if (t == 2) { src = x2; hw = 784;  obase = 2508800;  gidx = ( 40 + lb)*256 + c; }
    else             { src = x1; hw = 3136; obase = 10536960; gidx = r; }
    float scale = 1.f + gates[gidx];
    const float* row = src + (size_t)r * hw;
    float* orow = out + obase + (size_t)r * hw;
    if (hw == 49) {
        if (lane < 49) orow[lane] = row[lane] * scale;
    } else {
        int n4 = hw >> 2;
        for (int j = lane; j < n4; j += 64) {
            float4 v = *(const float4*)(row + j*4);
            v.x *= scale; v.y *= scale; v.z *= scale; v.w *= scale;
            *(float4*)(orow + j*4) = v;
        }
    }
}

extern "C" void kernel_launch(void* const* d_in, const int* in_sizes, int n_in,
                              void* d_out, int out_size, void* d_ws, size_t ws_size,
                              hipStream_t stream)
{
    const float* x1     = (const float*)d_in[0];
    const float* x2     = (const float*)d_in[1];
    const float* x3     = (const float*)d_in[2];
    const float* x4     = (const float*)d_in[3];
    const float* audio  = (const float*)d_in[4];
    const float* vis_w  = (const float*)d_in[5];
    const float* vis_b  = (const float*)d_in[6];
    const float* ln_g   = (const float*)d_in[7];
    const float* ln_b   = (const float*)d_in[8];
    const float* in_w   = (const float*)d_in[9];
    const float* conv_w = (const float*)d_in[10];
    const float* conv_b = (const float*)d_in[11];
    const float* xp_w   = (const float*)d_in[12];
    const float* dt_w   = (const float*)d_in[13];
    const float* dt_b   = (const float*)d_in[14];
    const float* A_log  = (const float*)d_in[15];
    const float* Dp     = (const float*)d_in[16];
    const float* out_w  = (const float*)d_in[17];
    const float* gate_w = (const float*)d_in[18];
    const float* gate_b = (const float*)d_in[19];

    float* ws  = (float*)d_ws;
    float* out = (float*)d_out;

    pool_kernel<<<dim3(10256), dim3(256), 0, stream>>>(x1, x2, x3, x4, audio, ws);
    build_kernel<<<dim3(256), dim3(256), 0, stream>>>(vis_w, vis_b, ws);
    for (int layer = 0; layer < 3; layer++) {
        lnxz_kernel<<<dim3(2048), dim3(256), 0, stream>>>(ln_g, ln_b, in_w, conv_w,
                                                          conv_b, ws, layer);
        dbl_kernel<<<dim3(256), dim3(256), 0, stream>>>(xp_w, ws, layer);
        scan_kernel<<<dim3(128), dim3(128), 0, stream>>>(dt_w, dt_b, A_log, Dp, ws, layer);
        out_kernel<<<dim3(512), dim3(256), 0, stream>>>(out_w, ws, layer);
    }
    gate_kernel<<<dim3(512), dim3(256), 0, stream>>>(gate_w, gate_b, ws);
    scale_ao_kernel<<<dim3(10280), dim3(256), 0, stream>>>(x1, x2, x3, x4, audio,
                                                           ws + WS_GATES, out);
}